// Round 9
// baseline (192.187 us; speedup 1.0000x reference)
//
#include <hip/hip_runtime.h>
#include <stdint.h>

#define H 256
#define EPS 1e-8f

typedef __bf16 bf16x8 __attribute__((ext_vector_type(8)));
typedef float  f32x4  __attribute__((ext_vector_type(4)));

__device__ __forceinline__ unsigned short f2bf(float f) {
  unsigned u = __builtin_bit_cast(unsigned, f);
  u += 0x7FFFu + ((u >> 16) & 1u);            // round-to-nearest-even
  return (unsigned short)(u >> 16);
}
__device__ __forceinline__ float bflo(unsigned u){ return __builtin_bit_cast(float, u << 16); }
__device__ __forceinline__ float bfhi(unsigned u){ return __builtin_bit_cast(float, u & 0xFFFF0000u); }

__device__ __forceinline__ uint4 pack8(float4 a, float4 b) {
  uint4 p;
  p.x = (unsigned)f2bf(a.x) | ((unsigned)f2bf(a.y) << 16);
  p.y = (unsigned)f2bf(a.z) | ((unsigned)f2bf(a.w) << 16);
  p.z = (unsigned)f2bf(b.x) | ((unsigned)f2bf(b.y) << 16);
  p.w = (unsigned)f2bf(b.z) | ((unsigned)f2bf(b.w) << 16);
  return p;
}

// Weight-stationary fused GEMM: Out = act(Asrc @ W^T + bias), swapped-MFMA
// (acc = mfma(Wfrag, Afrag) -> Out^T in regs: lane l16 = row, reg = col).
// FIRST:  Asrc = fp32 emb, act = relu, Out = hB (bf16).
// !FIRST: Asrc = bf16 hB, act = none, Out = gB, + rn[row] = 1/max(||g||,eps).
// W (256x256 bf16 = 128 KB) is loaded into LDS ONCE per block (reg-staged,
// fp32->bf16 in-kernel, XOR-swizzled); grid-stride over 128-row m-tiles.
// K-loop has NO weight staging: only the A-stream, 3-slot reg ring, 2-step
// lookahead (~700cyc = L3 latency), crossing lgkm-only raw barriers (A loads
// stay in flight across barriers - no vmcnt drain anywhere in the loop).
// Swizzles (both involutions, write+read sides identical - rule #21):
//   sW rows 512 B:  byte ^= ((row&7)<<4)      (was 16-way conflict)
//   sA rows  64 B:  byte ^= (((row>>1)&3)<<4) (was 8-way = the 2.2M counter)
// LDS: 128K (sW) + 2x8K (sA dbuf) + 1K (ssb) = 148480 B -> 1 block/CU, 8 waves.
#define SW_BYTES   131072
#define SA_BYTES   8192
#define LDS_BYTES  (SW_BYTES + 2 * SA_BYTES + 1024)
#define SA(b) (lds + SW_BYTES + (b) * SA_BYTES)

template<bool FIRST>
__global__ __launch_bounds__(512) void mlp_gemm_kernel(
    const void* __restrict__ Asrc, const float* __restrict__ Wf,
    const float* __restrict__ bias, unsigned short* __restrict__ Out,
    float* __restrict__ rn, int N, int ntiles) {
  extern __shared__ char lds[];
  char* sW = lds;
  float* ssb = (float*)(lds + SW_BYTES + 2 * SA_BYTES);  // [128][2]

  const int tid  = threadIdx.x;
  const int wave = tid >> 6, lane = tid & 63;
  const int quad = lane >> 4, l16 = lane & 15;
  const int wr = wave >> 1, wn = wave & 1;     // 8 waves: 4 row-groups x 2 col-halves

  // ---- W fill: fp32 -> bf16 into sW, swizzled, once per block ----
#pragma unroll 4
  for (int it = 0; it < 32; ++it) {
    int g = it * 512 + tid;                    // 16 B granule id, 16384 total
    int row = g >> 5;
    const float* src = Wf + (size_t)row * H + (g & 31) * 8;
    float4 w0 = *(const float4*)(src);
    float4 w1 = *(const float4*)(src + 4);
    uint4 p = pack8(w0, w1);
    unsigned off = ((unsigned)g * 16u) ^ (((unsigned)row & 7u) << 4);
    *(uint4*)(sW + off) = p;
  }
  // visibility: first k-iteration's lgkmcnt(0)+barrier covers these ds_writes

  // A staging geometry: thread -> granule (row = tid>>2, chunk = tid&3)
  const int arow = tid >> 2, ac = tid & 3;
  const unsigned aoff = ((unsigned)tid * 16u) ^ ((((unsigned)tid >> 3) & 3u) << 4);
  const float4 z4 = make_float4(0.f, 0.f, 0.f, 0.f);

  for (int t = blockIdx.x; t < ntiles; t += gridDim.x) {
    const int r0 = t * 128 + arow;
    const float* gA_f = nullptr; const unsigned short* gA_h = nullptr;
    bool avalid = true;
    if constexpr (FIRST) {
      avalid = r0 < N;
      gA_f = (const float*)Asrc + (size_t)(avalid ? r0 : N - 1) * H + ac * 8;
    } else {
      gA_h = (const unsigned short*)Asrc + (size_t)r0 * H + ac * 8;
    }

    float4 rf[3][2]; uint4 rh[3];
#define LOADA(kt, s)                                                            \
    do {                                                                        \
      if constexpr (FIRST) {                                                    \
        rf[s][0] = *(const float4*)(gA_f + (kt) * 32);                          \
        rf[s][1] = *(const float4*)(gA_f + (kt) * 32 + 4);                      \
      } else {                                                                  \
        rh[s] = *(const uint4*)(gA_h + (kt) * 32);                              \
      }                                                                         \
    } while (0)
#define WRITEA(s, bufp)                                                         \
    do {                                                                        \
      uint4 p;                                                                  \
      if constexpr (FIRST) {                                                    \
        float4 t0 = avalid ? rf[s][0] : z4;                                     \
        float4 t1 = avalid ? rf[s][1] : z4;                                     \
        p = pack8(t0, t1);                                                      \
      } else { p = rh[s]; }                                                     \
      *(uint4*)((bufp) + aoff) = p;                                             \
    } while (0)

    // prologue: A(0..2) in flight, A(0) staged to buf0
    LOADA(0, 0); LOADA(1, 1); LOADA(2, 2);
    WRITEA(0, SA(0));

    f32x4 acc[8][2];
#pragma unroll
    for (int i = 0; i < 8; i++)
#pragma unroll
      for (int j = 0; j < 2; j++) acc[i][j] = (f32x4){0.f, 0.f, 0.f, 0.f};

#pragma unroll
    for (int kt = 0; kt < 8; ++kt) {
      // lgkm-only barrier: prior ds ops retired + visible; A global loads
      // (vmcnt) stay in flight across it.
      asm volatile("s_waitcnt lgkmcnt(0)" ::: "memory");
      __builtin_amdgcn_s_barrier();
      if (kt < 5) LOADA(kt + 3, kt % 3);               // 2-step-lookahead ring
      if (kt < 7) WRITEA((kt + 1) % 3, SA((kt + 1) & 1));

      bf16x8 wf[8], af0, af1;
#pragma unroll
      for (int i = 0; i < 8; i++) {
        unsigned wrow = (unsigned)(wn * 128 + i * 16 + l16);
        unsigned woff = (wrow * 512u + (unsigned)kt * 64u + (unsigned)quad * 16u)
                        ^ ((wrow & 7u) << 4);
        wf[i] = *(const bf16x8*)(sW + woff);
      }
      {
        unsigned ar0 = (unsigned)(wr * 32 + l16), ar1 = ar0 + 16;
        const char* ab = SA(kt & 1);
        af0 = *(const bf16x8*)(ab + ((ar0 * 64u + (unsigned)quad * 16u) ^ (((ar0 >> 1) & 3u) << 4)));
        af1 = *(const bf16x8*)(ab + ((ar1 * 64u + (unsigned)quad * 16u) ^ (((ar1 >> 1) & 3u) << 4)));
      }
#pragma unroll
      for (int i = 0; i < 8; i++) {
        acc[i][0] = __builtin_amdgcn_mfma_f32_16x16x32_bf16(wf[i], af0, acc[i][0], 0, 0, 0);
        acc[i][1] = __builtin_amdgcn_mfma_f32_16x16x32_bf16(wf[i], af1, acc[i][1], 0, 0, 0);
      }
    }

    // epilogue: +bias, (relu | rownorm), packed 4-col bf16 stores
    // layout (m89/m91-verified, rounds 4-8 passed): lane l16 = row, reg = col
    float ss0 = 0.f, ss1 = 0.f;
#pragma unroll
    for (int i = 0; i < 8; i++) {
      const int col0 = wn * 128 + i * 16 + quad * 4;
      const float4 bv = *(const float4*)(bias + col0);
#pragma unroll
      for (int j = 0; j < 2; j++) {
        const int row = t * 128 + wr * 32 + j * 16 + l16;
        f32x4 v = acc[i][j];
        float v0 = v[0] + bv.x, v1 = v[1] + bv.y, v2 = v[2] + bv.z, v3 = v[3] + bv.w;
        if constexpr (FIRST) {
          v0 = fmaxf(v0, 0.f); v1 = fmaxf(v1, 0.f);
          v2 = fmaxf(v2, 0.f); v3 = fmaxf(v3, 0.f);
        } else {
          float s = v0 * v0 + v1 * v1 + v2 * v2 + v3 * v3;
          if (j == 0) ss0 += s; else ss1 += s;
        }
        uint2 p;
        p.x = (unsigned)f2bf(v0) | ((unsigned)f2bf(v1) << 16);
        p.y = (unsigned)f2bf(v2) | ((unsigned)f2bf(v3) << 16);
        *(uint2*)(Out + (size_t)row * H + col0) = p;
      }
    }
    if constexpr (!FIRST) {
      // reduce across the 4 quads (lanes l16, +16, +32, +48), then across wn
      ss0 += __shfl_xor(ss0, 16, 64); ss0 += __shfl_xor(ss0, 32, 64);
      ss1 += __shfl_xor(ss1, 16, 64); ss1 += __shfl_xor(ss1, 32, 64);
      if (quad == 0) {
        ssb[(wr * 32 + l16) * 2 + wn]      = ss0;
        ssb[(wr * 32 + 16 + l16) * 2 + wn] = ss1;
      }
      __syncthreads();
      if (tid < 128) {
        float s2 = ssb[tid * 2 + 0] + ssb[tid * 2 + 1];
        rn[t * 128 + tid] = 1.f / fmaxf(sqrtf(s2), EPS);
      }
      // next tile's ssb writes are separated by >=1 kt-barrier with lgkmcnt(0)
    }
#undef LOADA
#undef WRITEA
  }
}

__device__ __forceinline__ float dot_u4(uint4 a, uint4 b) {
  float s;
  s  = bflo(a.x) * bflo(b.x) + bfhi(a.x) * bfhi(b.x);
  s += bflo(a.y) * bflo(b.y) + bfhi(a.y) * bfhi(b.y);
  s += bflo(a.z) * bflo(b.z) + bfhi(a.z) * bfhi(b.z);
  s += bflo(a.w) * bflo(b.w) + bfhi(a.w) * bfhi(b.w);
  return s;
}

// 8 lanes per edge, 8 edges per wave, 32 edges per block.
__global__ __launch_bounds__(256) void edge_cos_kernel(
    const int* __restrict__ ei, const unsigned short* __restrict__ g,
    const float* __restrict__ rn, float* __restrict__ out, int E) {
  const int lane = threadIdx.x & 63;
  const int wid  = threadIdx.x >> 6;
  const int l8   = lane & 7;
  const int sub  = lane >> 3;
  const int e    = blockIdx.x * 32 + wid * 8 + sub;
  if (e >= E) return;
  const int c = ei[e], r = ei[E + e];
  const uint4* gc = (const uint4*)(g + (size_t)c * H);
  const uint4* gr = (const uint4*)(g + (size_t)r * H);
  uint4 a0 = gc[l8], a1 = gc[l8 + 8], a2 = gc[l8 + 16], a3 = gc[l8 + 24];
  uint4 b0 = gr[l8], b1 = gr[l8 + 8], b2 = gr[l8 + 16], b3 = gr[l8 + 24];
  float d = dot_u4(a0, b0) + dot_u4(a1, b1) + dot_u4(a2, b2) + dot_u4(a3, b3);
  d += __shfl_xor(d, 4, 8);
  d += __shfl_xor(d, 2, 8);
  d += __shfl_xor(d, 1, 8);
  if (l8 == 0) out[e] = d * rn[c] * rn[r];
}

extern "C" void kernel_launch(void* const* d_in, const int* in_sizes, int n_in,
                              void* d_out, int out_size, void* d_ws, size_t ws_size,
                              hipStream_t stream) {
  const float* emb = (const float*)d_in[0];
  const int*   ei  = (const int*)d_in[1];
  const float* W1  = (const float*)d_in[2];
  const float* b1  = (const float*)d_in[3];
  const float* W2  = (const float*)d_in[4];
  const float* b2  = (const float*)d_in[5];
  float* out = (float*)d_out;

  const int NH = in_sizes[0];                // N*H
  const int N  = NH / H;                     // 50000
  const int E  = in_sizes[1] / 2;            // 300000
  const int Mp = ((N + 127) / 128) * 128;    // 50048 (391 tiles of 128 rows)
  const int ntiles = Mp / 128;

  char* ws = (char*)d_ws;
  unsigned short* hB = (unsigned short*)ws; ws += (size_t)Mp * H * 2;
  unsigned short* gB = (unsigned short*)ws; ws += (size_t)Mp * H * 2;
  float* rn          = (float*)ws;

  static bool attr_set = false;
  if (!attr_set) {
    hipFuncSetAttribute(reinterpret_cast<const void*>(mlp_gemm_kernel<true>),
                        hipFuncAttributeMaxDynamicSharedMemorySize, LDS_BYTES);
    hipFuncSetAttribute(reinterpret_cast<const void*>(mlp_gemm_kernel<false>),
                        hipFuncAttributeMaxDynamicSharedMemorySize, LDS_BYTES);
    attr_set = true;
  }

  mlp_gemm_kernel<true ><<<256, 512, LDS_BYTES, stream>>>(emb, W1, b1, hB, nullptr, N, ntiles);
  mlp_gemm_kernel<false><<<256, 512, LDS_BYTES, stream>>>(hB,  W2, b2, gB, rn,      N, ntiles);
  edge_cos_kernel<<<(E + 31) / 32, 256, 0, stream>>>(ei, gB, rn, out, E);
}

// Round 10
// 170.100 us; speedup vs baseline: 1.1298x; 1.1298x over previous
//
#include <hip/hip_runtime.h>
#include <stdint.h>

#define H 256
#define EPS 1e-8f

typedef __bf16 bf16x8 __attribute__((ext_vector_type(8)));
typedef float  f32x4  __attribute__((ext_vector_type(4)));

__device__ __forceinline__ unsigned short f2bf(float f) {
  unsigned u = __builtin_bit_cast(unsigned, f);
  u += 0x7FFFu + ((u >> 16) & 1u);            // round-to-nearest-even
  return (unsigned short)(u >> 16);
}
__device__ __forceinline__ float bflo(unsigned u){ return __builtin_bit_cast(float, u << 16); }
__device__ __forceinline__ float bfhi(unsigned u){ return __builtin_bit_cast(float, u & 0xFFFF0000u); }

// both 256x256 weight matrices in one launch (grid = 2*H*H/4/256 = 128)
__global__ __launch_bounds__(256) void conv_w_kernel(
    const float* __restrict__ W1, const float* __restrict__ W2,
    unsigned short* __restrict__ w1B, unsigned short* __restrict__ w2B) {
  int i = (blockIdx.x * 256 + threadIdx.x) * 4;
  const int HH = H * H;
  if (i >= 2 * HH) return;
  const float* s = (i < HH) ? W1 : W2;
  unsigned short* d = (i < HH) ? w1B : w2B;
  int j = (i < HH) ? i : i - HH;
  float4 v = *(const float4*)(s + j);
  ushort4 o;
  o.x = f2bf(v.x); o.y = f2bf(v.y); o.z = f2bf(v.z); o.w = f2bf(v.w);
  *(ushort4*)(d + j) = o;
}

// Fused MLP: g = relu(emb@W1^T + b1)@W2^T + b2, plus rn[i] = 1/max(||g_i||,eps).
// Round-10 = round-5/8 structure with W REG-STAGED (T14): W tiles load
// global->VGPR ring (2 slots, issued ~1.5 steps before use) -> ds_write ->
// lgkm-ONLY raw barriers. NO barrier in either K-loop drains vmcnt, so the
// W ring and the 3-slot A ring stay in flight continuously (rounds 5/8's
// vmcnt waits at each step were the ~74% stall: MfmaUtil+VALUBusy ~26%).
// Ring schedule (verified slot-free-at-load):
//   GEMM1 step kt: load W1(kt+2)->slot kt&1 ; write W1(kt+1) from slot (kt+1)&1
//                  load A(kt+3)->slot kt%3  ; write A(kt+1) from slot (kt+1)%3
//   kt=6: load W2(0)->slot0 ; kt=7: write W2(0)->sW[0], load W2(1)->slot1
//   GEMM2 step kt: load W2(kt+2)->slot kt&1 ; write W2(kt+1) from slot (kt+1)&1
// All loop indices compile-time (full unroll) -> no scratch (rule #20).
// LDS 8+32+32+0.5 = 72.5 KB static -> 2 blocks/CU.
__global__ __launch_bounds__(256) void fused_mlp_kernel(
    const float* __restrict__ Af,           // emb fp32 [N][H]
    const unsigned short* __restrict__ W1,  // [H][H] bf16, row = out-col
    const unsigned short* __restrict__ W2,
    const float* __restrict__ b1, const float* __restrict__ b2,
    unsigned short* __restrict__ G,         // gB out [Mp][H] bf16
    float* __restrict__ rn, int N) {
  __shared__ unsigned short sA[2][64 * 32];   // 8 KB  emb tile (dbuf)
  __shared__ unsigned short sW[2][256 * 32];  // 32 KB weight tile (dbuf, W1 then W2)
  __shared__ unsigned short sH[64 * 256];     // 32 KB h (swizzled)
  __shared__ float ssb[64][2];                // rownorm partials per col-half

  const int tid  = threadIdx.x;
  const int wave = tid >> 6, lane = tid & 63;
  const int quad = lane >> 4, l16 = lane & 15;
  const int wr = wave >> 1, wn = wave & 1;
  const size_t bm = blockIdx.x;

  // staging geometry: thread -> (row, 8-elem k-chunk); sA/sW row-major [r][32]
  const int arow = tid >> 2, kch = (tid & 3) * 8;
  const int grow = (int)bm * 64 + arow;
  const bool avalid = grow < N;
  const int crow = avalid ? grow : (N - 1);   // clamp: A load always issued
  const float* gAf = Af + (size_t)crow * H + kch;
  const unsigned short* gW1 = W1 + (size_t)arow * H + kch;
  const unsigned short* gW2 = W2 + (size_t)arow * H + kch;

  const float4 z4 = make_float4(0.f, 0.f, 0.f, 0.f);
  float4 rf[3][2];   // A ring (3 slots, ~2.5-step lookahead)
  uint4  rw[2][4];   // W ring (2 slots, ~1.5-step lookahead)

#define LOADA(kt, s)                                                            \
  do {                                                                          \
    rf[s][0] = *(const float4*)(gAf + (kt) * 32);                               \
    rf[s][1] = *(const float4*)(gAf + (kt) * 32 + 4);                           \
  } while (0)
#define WRITEA(s, buf)                                                          \
  do {                                                                          \
    float4 t0 = avalid ? rf[s][0] : z4;                                         \
    float4 t1 = avalid ? rf[s][1] : z4;                                         \
    uint4 p;                                                                    \
    p.x = (unsigned)f2bf(t0.x) | ((unsigned)f2bf(t0.y) << 16);                  \
    p.y = (unsigned)f2bf(t0.z) | ((unsigned)f2bf(t0.w) << 16);                  \
    p.z = (unsigned)f2bf(t1.x) | ((unsigned)f2bf(t1.y) << 16);                  \
    p.w = (unsigned)f2bf(t1.z) | ((unsigned)f2bf(t1.w) << 16);                  \
    *(uint4*)(&sA[buf][tid * 8]) = p;                                           \
  } while (0)
#define LOADW(gW, kt, s)                                                        \
  do {                                                                          \
    _Pragma("unroll")                                                           \
    for (int c = 0; c < 4; c++)                                                 \
      rw[s][c] = *(const uint4*)((gW) + (size_t)(c * 64) * H + (kt) * 32);      \
  } while (0)
#define WRITEW(s, buf)                                                          \
  do {                                                                          \
    _Pragma("unroll")                                                           \
    for (int c = 0; c < 4; c++)                                                 \
      *(uint4*)(&sW[buf][c * 2048 + tid * 8]) = rw[s][c];                       \
  } while (0)
#define LGKM_BAR()                                                              \
  do {                                                                          \
    asm volatile("s_waitcnt lgkmcnt(0)" ::: "memory");                          \
    __builtin_amdgcn_s_barrier();                                               \
  } while (0)

  // ---------------- GEMM1 (swapped): acc[iC][jR] = h^T subtiles -------------
  f32x4 acc[8][2];
#pragma unroll
  for (int i = 0; i < 8; i++)
#pragma unroll
    for (int j = 0; j < 2; j++) acc[i][j] = (f32x4){0.f, 0.f, 0.f, 0.f};

  // prologue: W1(0),W1(1) + A(0..2) in flight; tile-0 staged; lgkm barrier only
  LOADW(gW1, 0, 0);
  LOADW(gW1, 1, 1);
  LOADA(0, 0); LOADA(1, 1); LOADA(2, 2);
  WRITEW(0, 0);
  WRITEA(0, 0);
  LGKM_BAR();

#pragma unroll
  for (int kt = 0; kt < 8; ++kt) {
    if (kt) LGKM_BAR();                      // prior ds ops visible; vmcnt untouched
    if (kt < 6) LOADW(gW1, kt + 2, kt & 1);  // slot freed by write at kt-1
    if (kt == 6) LOADW(gW2, 0, 0);           // W2(0) -> slot0 (freed at kt=5)
    if (kt == 7) LOADW(gW2, 1, 1);           // W2(1) -> slot1 (freed at kt=6)
    if (kt < 5) LOADA(kt + 3, kt % 3);

    bf16x8 wf[8], af0, af1;
#pragma unroll
    for (int i = 0; i < 8; i++)
      wf[i] = *(const bf16x8*)(&sW[kt & 1][(wn * 128 + i * 16 + l16) * 32 + quad * 8]);
    af0 = *(const bf16x8*)(&sA[kt & 1][(wr * 32 + 0 * 16 + l16) * 32 + quad * 8]);
    af1 = *(const bf16x8*)(&sA[kt & 1][(wr * 32 + 1 * 16 + l16) * 32 + quad * 8]);

    if (kt < 7) {
      WRITEW((kt + 1) & 1, (kt + 1) & 1);    // W1(kt+1), regs loaded at kt-1
      WRITEA((kt + 1) % 3, (kt + 1) & 1);    // A(kt+1), regs loaded at kt-2
    } else {
      WRITEW(0, 0);                          // W2(0) -> sW[0] (reads of sW[0] ended kt=6)
    }

#pragma unroll
    for (int i = 0; i < 8; i++) {
      acc[i][0] = __builtin_amdgcn_mfma_f32_16x16x32_bf16(wf[i], af0, acc[i][0], 0, 0, 0);
      acc[i][1] = __builtin_amdgcn_mfma_f32_16x16x32_bf16(wf[i], af1, acc[i][1], 0, 0, 0);
    }
  }

  // ------------- h epilogue: +b1, relu, bf16, packed b64 into sH ------------
  // layout (m89/m91-verified, rounds 4-8 passed): lane l16 = h-row, reg = h-col
#pragma unroll
  for (int i = 0; i < 8; i++) {
    const int hcol = wn * 128 + i * 16 + quad * 4;
    const float4 bv = *(const float4*)(b1 + hcol);
#pragma unroll
    for (int j = 0; j < 2; j++) {
      const int row = wr * 32 + j * 16 + l16;
      f32x4 v = acc[i][j];
      unsigned short h0 = f2bf(fmaxf(v[0] + bv.x, 0.f));
      unsigned short h1 = f2bf(fmaxf(v[1] + bv.y, 0.f));
      unsigned short h2 = f2bf(fmaxf(v[2] + bv.z, 0.f));
      unsigned short h3 = f2bf(fmaxf(v[3] + bv.w, 0.f));
      uint2 p;
      p.x = (unsigned)h0 | ((unsigned)h1 << 16);
      p.y = (unsigned)h2 | ((unsigned)h3 << 16);
      unsigned off = (unsigned)(row * 512 + hcol * 2) ^ ((unsigned)(row & 7) << 4);
      *(uint2*)((char*)sH + off) = p;
    }
  }

  LGKM_BAR();   // sH + W2(0) visible; W2(1) load still in flight

  // ---------------- GEMM2 (normal): acc2[iR][j] = g subtiles ----------------
  f32x4 acc2[2][8];
#pragma unroll
  for (int i = 0; i < 2; i++)
#pragma unroll
    for (int j = 0; j < 8; j++) acc2[i][j] = (f32x4){0.f, 0.f, 0.f, 0.f};

#pragma unroll
  for (int kt = 0; kt < 8; ++kt) {
    if (kt) LGKM_BAR();
    if (kt < 6) LOADW(gW2, kt + 2, kt & 1);  // kt=0: W2(2)->slot0 (freed at G1 kt=7)

    bf16x8 wf2[8], hf[2];
#pragma unroll
    for (int j = 0; j < 8; j++)
      wf2[j] = *(const bf16x8*)(&sW[kt & 1][(wn * 128 + j * 16 + l16) * 32 + quad * 8]);
#pragma unroll
    for (int i = 0; i < 2; i++) {
      const int hrow = wr * 32 + i * 16 + l16;
      unsigned off = (unsigned)(hrow * 512 + kt * 64 + quad * 16) ^ ((unsigned)(hrow & 7) << 4);
      hf[i] = *(const bf16x8*)((const char*)sH + off);
    }

    if (kt < 7) WRITEW((kt + 1) & 1, (kt + 1) & 1);  // W2(kt+1), regs from kt-1

#pragma unroll
    for (int i = 0; i < 2; i++)
#pragma unroll
      for (int j = 0; j < 8; j++)
        acc2[i][j] = __builtin_amdgcn_mfma_f32_16x16x32_bf16(hf[i], wf2[j], acc2[i][j], 0, 0, 0);
  }

  // --------- final epilogue: +b2, rownorm (in-block), bf16 g writes ---------
  float b2v[8];
#pragma unroll
  for (int j = 0; j < 8; j++) b2v[j] = b2[wn * 128 + j * 16 + l16];
#pragma unroll
  for (int i = 0; i < 2; i++)
#pragma unroll
    for (int j = 0; j < 8; j++)
#pragma unroll
      for (int r = 0; r < 4; r++) acc2[i][j][r] += b2v[j];

  float ss[2][4];
#pragma unroll
  for (int i = 0; i < 2; i++)
#pragma unroll
    for (int r = 0; r < 4; r++) {
      float s = 0.f;
#pragma unroll
      for (int j = 0; j < 8; j++) s += acc2[i][j][r] * acc2[i][j][r];
      ss[i][r] = s;
    }
#pragma unroll
  for (int m = 1; m < 16; m <<= 1)
#pragma unroll
    for (int i = 0; i < 2; i++)
#pragma unroll
      for (int r = 0; r < 4; r++) ss[i][r] += __shfl_xor(ss[i][r], m, 64);
  if (l16 == 0) {
#pragma unroll
    for (int i = 0; i < 2; i++)
#pragma unroll
      for (int r = 0; r < 4; r++) ssb[wr * 32 + i * 16 + quad * 4 + r][wn] = ss[i][r];
  }
  __syncthreads();   // rownorm combine (full drain fine here)
  if (tid < 64) {
    float s2 = ssb[tid][0] + ssb[tid][1];
    rn[bm * 64 + tid] = 1.f / fmaxf(sqrtf(s2), EPS);
  }

#pragma unroll
  for (int i = 0; i < 2; i++)
#pragma unroll
    for (int j = 0; j < 8; j++) {
      const int gcol = wn * 128 + j * 16 + l16;
#pragma unroll
      for (int r = 0; r < 4; r++) {
        const size_t grow2 = bm * 64 + wr * 32 + i * 16 + quad * 4 + r;
        G[grow2 * H + gcol] = f2bf(acc2[i][j][r]);
      }
    }
#undef LOADA
#undef WRITEA
#undef LOADW
#undef WRITEW
#undef LGKM_BAR
}

__device__ __forceinline__ float dot_u4(uint4 a, uint4 b) {
  float s;
  s  = bflo(a.x) * bflo(b.x) + bfhi(a.x) * bfhi(b.x);
  s += bflo(a.y) * bflo(b.y) + bfhi(a.y) * bfhi(b.y);
  s += bflo(a.z) * bflo(b.z) + bfhi(a.z) * bfhi(b.z);
  s += bflo(a.w) * bflo(b.w) + bfhi(a.w) * bfhi(b.w);
  return s;
}

// 8 lanes per edge, 8 edges per wave, 32 edges per block.
__global__ __launch_bounds__(256) void edge_cos_kernel(
    const int* __restrict__ ei, const unsigned short* __restrict__ g,
    const float* __restrict__ rn, float* __restrict__ out, int E) {
  const int lane = threadIdx.x & 63;
  const int wid  = threadIdx.x >> 6;
  const int l8   = lane & 7;
  const int sub  = lane >> 3;
  const int e    = blockIdx.x * 32 + wid * 8 + sub;
  if (e >= E) return;
  const int c = ei[e], r = ei[E + e];
  const uint4* gc = (const uint4*)(g + (size_t)c * H);
  const uint4* gr = (const uint4*)(g + (size_t)r * H);
  uint4 a0 = gc[l8], a1 = gc[l8 + 8], a2 = gc[l8 + 16], a3 = gc[l8 + 24];
  uint4 b0 = gr[l8], b1 = gr[l8 + 8], b2 = gr[l8 + 16], b3 = gr[l8 + 24];
  float d = dot_u4(a0, b0) + dot_u4(a1, b1) + dot_u4(a2, b2) + dot_u4(a3, b3);
  d += __shfl_xor(d, 4, 8);
  d += __shfl_xor(d, 2, 8);
  d += __shfl_xor(d, 1, 8);
  if (l8 == 0) out[e] = d * rn[c] * rn[r];
}

extern "C" void kernel_launch(void* const* d_in, const int* in_sizes, int n_in,
                              void* d_out, int out_size, void* d_ws, size_t ws_size,
                              hipStream_t stream) {
  const float* emb = (const float*)d_in[0];
  const int*   ei  = (const int*)d_in[1];
  const float* W1  = (const float*)d_in[2];
  const float* b1  = (const float*)d_in[3];
  const float* W2  = (const float*)d_in[4];
  const float* b2  = (const float*)d_in[5];
  float* out = (float*)d_out;

  const int NH = in_sizes[0];              // N*H
  const int N  = NH / H;                   // 50000
  const int E  = in_sizes[1] / 2;          // 300000
  const int Mp = ((N + 63) / 64) * 64;     // 50048 (multiple of 64)

  char* ws = (char*)d_ws;
  unsigned short* gB   = (unsigned short*)ws; ws += (size_t)Mp * H * 2;
  unsigned short* w1B  = (unsigned short*)ws; ws += (size_t)H * H * 2;
  unsigned short* w2B  = (unsigned short*)ws; ws += (size_t)H * H * 2;
  float* rn            = (float*)ws;

  conv_w_kernel<<<(2 * H * H / 4 + 255) / 256, 256, 0, stream>>>(W1, W2, w1B, w2B);

  fused_mlp_kernel<<<Mp / 64, 256, 0, stream>>>(emb, w1B, w2B, b1, b2, gB, rn, N);

  edge_cos_kernel<<<(E + 31) / 32, 256, 0, stream>>>(ei, gB, rn, out, E);
}

// Round 11
// 157.548 us; speedup vs baseline: 1.2199x; 1.0797x over previous
//
#include <hip/hip_runtime.h>
#include <stdint.h>

#define H 256
#define EPS 1e-8f

typedef __bf16 bf16x8 __attribute__((ext_vector_type(8)));
typedef float  f32x4  __attribute__((ext_vector_type(4)));

__device__ __forceinline__ unsigned short f2bf(float f) {
  unsigned u = __builtin_bit_cast(unsigned, f);
  u += 0x7FFFu + ((u >> 16) & 1u);            // round-to-nearest-even
  return (unsigned short)(u >> 16);
}
__device__ __forceinline__ float bflo(unsigned u){ return __builtin_bit_cast(float, u << 16); }
__device__ __forceinline__ float bfhi(unsigned u){ return __builtin_bit_cast(float, u & 0xFFFF0000u); }

__device__ __forceinline__ void g2l16(const void* g, void* l) {
  __builtin_amdgcn_global_load_lds((__attribute__((address_space(1))) void*)g,
                                   (__attribute__((address_space(3))) void*)l, 16, 0, 0);
}

// both 256x256 weight matrices in one launch (grid = 2*H*H/4/256 = 128)
__global__ __launch_bounds__(256) void conv_w_kernel(
    const float* __restrict__ W1, const float* __restrict__ W2,
    unsigned short* __restrict__ w1B, unsigned short* __restrict__ w2B) {
  int i = (blockIdx.x * 256 + threadIdx.x) * 4;
  const int HH = H * H;
  if (i >= 2 * HH) return;
  const float* s = (i < HH) ? W1 : W2;
  unsigned short* d = (i < HH) ? w1B : w2B;
  int j = (i < HH) ? i : i - HH;
  float4 v = *(const float4*)(s + j);
  ushort4 o;
  o.x = f2bf(v.x); o.y = f2bf(v.y); o.z = f2bf(v.z); o.w = f2bf(v.w);
  *(ushort4*)(d + j) = o;
}

// Fused MLP: g = relu(emb@W1^T + b1)@W2^T + b2, plus rn[i] = 1/max(||g_i||,eps).
// Round-11: OCCUPANCY attack. Rounds 4-10 ledger: every intra-wave schedule
// variant (serial / dbuf / counted-vmcnt / reg-rings) lands at 40-56us with
// the SAME ~75% stall and the SAME 2 blocks/CU (LDS 72.5KB). m114: latency
// here is hidden by inter-block TLP, not intra-wave ILP. So: LDS diet.
// Single-buffered sA (4KB) + single sW (16KB, staged per k-step, W1 then W2)
// + sH (32KB) + ssb = 53.75 KB -> 3 blocks/CU (12 waves/CU), +50% TLP.
// Schedule = round-4's proven serial {sync; stage; sync; compute} (measured
// best of all variants). A loads fp32 emb directly (round-5's pack path).
// All MFMA fragment + epilogue layouts byte-identical to rounds 4-10 (passed).
__global__ __launch_bounds__(256, 4) void fused_mlp_kernel(
    const float* __restrict__ Af,           // emb fp32 [N][H]
    const unsigned short* __restrict__ W1,  // [H][H] bf16, row = out-col
    const unsigned short* __restrict__ W2,
    const float* __restrict__ b1, const float* __restrict__ b2,
    unsigned short* __restrict__ G,         // gB out [Mp][H] bf16
    float* __restrict__ rn, int N) {
  __shared__ unsigned short sA[64 * 32];     // 4 KB  emb tile (single)
  __shared__ unsigned short sW[256 * 32];    // 16 KB weight k-tile (single)
  __shared__ unsigned short sH[64 * 256];    // 32 KB h (swizzled)
  __shared__ float ssb[64][2];               // rownorm partials per col-half

  const int tid  = threadIdx.x;
  const int wave = tid >> 6, lane = tid & 63;
  const int quad = lane >> 4, l16 = lane & 15;
  const int wr = wave >> 1, wn = wave & 1;
  const size_t bm = blockIdx.x;

  // staging geometry: thread -> (row = tid>>2, 8-elem k-chunk = tid&3)
  const int arow = tid >> 2, kch = (tid & 3) * 8;
  const int grow = (int)bm * 64 + arow;
  const bool avalid = grow < N;
  const int crow = avalid ? grow : (N - 1);   // clamp; zero-select at pack
  const float* gAf = Af + (size_t)crow * H + kch;
  const unsigned short* gW1 = W1 + (size_t)arow * H + kch;
  const unsigned short* gW2 = W2 + (size_t)arow * H + kch;
  const float4 z4 = make_float4(0.f, 0.f, 0.f, 0.f);

#define STAGE_A(kt)                                                             \
  do {                                                                          \
    float4 a0 = *(const float4*)(gAf + (kt) * 32);                              \
    float4 a1 = *(const float4*)(gAf + (kt) * 32 + 4);                          \
    if (!avalid) { a0 = z4; a1 = z4; }                                          \
    uint4 p;                                                                    \
    p.x = (unsigned)f2bf(a0.x) | ((unsigned)f2bf(a0.y) << 16);                  \
    p.y = (unsigned)f2bf(a0.z) | ((unsigned)f2bf(a0.w) << 16);                  \
    p.z = (unsigned)f2bf(a1.x) | ((unsigned)f2bf(a1.y) << 16);                  \
    p.w = (unsigned)f2bf(a1.z) | ((unsigned)f2bf(a1.w) << 16);                  \
    *(uint4*)(&sA[tid * 8]) = p;                                                \
  } while (0)
#define STAGE_W(gW, kt)                                                         \
  do {                                                                          \
    _Pragma("unroll")                                                           \
    for (int c = 0; c < 4; c++)                                                 \
      g2l16((gW) + (size_t)(c * 64) * H + (kt) * 32, &sW[c * 2048 + tid * 8]);  \
  } while (0)

  // ---------------- GEMM1 (swapped): acc[iC][jR] = h^T subtiles -------------
  f32x4 acc[8][2];
#pragma unroll
  for (int i = 0; i < 8; i++)
#pragma unroll
    for (int j = 0; j < 2; j++) acc[i][j] = (f32x4){0.f, 0.f, 0.f, 0.f};

#pragma unroll
  for (int kt = 0; kt < 8; ++kt) {
    if (kt) __syncthreads();                 // prior reads done before overwrite
    STAGE_A(kt);                             // fp32 loads issued first
    STAGE_W(gW1, kt);                        // 4x g2l16
    __syncthreads();                         // stage drained, tiles visible

    bf16x8 wf[8], af0, af1;
#pragma unroll
    for (int i = 0; i < 8; i++)
      wf[i] = *(const bf16x8*)(&sW[(wn * 128 + i * 16 + l16) * 32 + quad * 8]);
    af0 = *(const bf16x8*)(&sA[(wr * 32 + 0 * 16 + l16) * 32 + quad * 8]);
    af1 = *(const bf16x8*)(&sA[(wr * 32 + 1 * 16 + l16) * 32 + quad * 8]);

#pragma unroll
    for (int i = 0; i < 8; i++) {
      acc[i][0] = __builtin_amdgcn_mfma_f32_16x16x32_bf16(wf[i], af0, acc[i][0], 0, 0, 0);
      acc[i][1] = __builtin_amdgcn_mfma_f32_16x16x32_bf16(wf[i], af1, acc[i][1], 0, 0, 0);
    }
  }

  // ------------- h epilogue: +b1, relu, bf16, packed b64 into sH ------------
  // layout (m89/m91-verified, rounds 4-10 passed): lane l16 = h-row, reg = h-col
#pragma unroll
  for (int i = 0; i < 8; i++) {
    const int hcol = wn * 128 + i * 16 + quad * 4;
    const float4 bv = *(const float4*)(b1 + hcol);
#pragma unroll
    for (int j = 0; j < 2; j++) {
      const int row = wr * 32 + j * 16 + l16;
      f32x4 v = acc[i][j];
      unsigned short h0 = f2bf(fmaxf(v[0] + bv.x, 0.f));
      unsigned short h1 = f2bf(fmaxf(v[1] + bv.y, 0.f));
      unsigned short h2 = f2bf(fmaxf(v[2] + bv.z, 0.f));
      unsigned short h3 = f2bf(fmaxf(v[3] + bv.w, 0.f));
      uint2 p;
      p.x = (unsigned)h0 | ((unsigned)h1 << 16);
      p.y = (unsigned)h2 | ((unsigned)h3 << 16);
      unsigned off = (unsigned)(row * 512 + hcol * 2) ^ ((unsigned)(row & 7) << 4);
      *(uint2*)((char*)sH + off) = p;
    }
  }

  __syncthreads();   // sH visible; GEMM1's sW reads complete (safe to overwrite)

  // ---------------- GEMM2 (normal): acc2[iR][j] = g subtiles ----------------
  f32x4 acc2[2][8];
#pragma unroll
  for (int i = 0; i < 2; i++)
#pragma unroll
    for (int j = 0; j < 8; j++) acc2[i][j] = (f32x4){0.f, 0.f, 0.f, 0.f};

#pragma unroll
  for (int kt = 0; kt < 8; ++kt) {
    if (kt) __syncthreads();
    STAGE_W(gW2, kt);
    __syncthreads();

    bf16x8 wf2[8], hf[2];
#pragma unroll
    for (int j = 0; j < 8; j++)
      wf2[j] = *(const bf16x8*)(&sW[(wn * 128 + j * 16 + l16) * 32 + quad * 8]);
#pragma unroll
    for (int i = 0; i < 2; i++) {
      const int hrow = wr * 32 + i * 16 + l16;
      unsigned off = (unsigned)(hrow * 512 + kt * 64 + quad * 16) ^ ((unsigned)(hrow & 7) << 4);
      hf[i] = *(const bf16x8*)((const char*)sH + off);
    }
#pragma unroll
    for (int i = 0; i < 2; i++)
#pragma unroll
      for (int j = 0; j < 8; j++)
        acc2[i][j] = __builtin_amdgcn_mfma_f32_16x16x32_bf16(hf[i], wf2[j], acc2[i][j], 0, 0, 0);
  }

  // --------- final epilogue: +b2, rownorm (in-block), bf16 g writes ---------
  float b2v[8];
#pragma unroll
  for (int j = 0; j < 8; j++) b2v[j] = b2[wn * 128 + j * 16 + l16];
#pragma unroll
  for (int i = 0; i < 2; i++)
#pragma unroll
    for (int j = 0; j < 8; j++)
#pragma unroll
      for (int r = 0; r < 4; r++) acc2[i][j][r] += b2v[j];

  float ss[2][4];
#pragma unroll
  for (int i = 0; i < 2; i++)
#pragma unroll
    for (int r = 0; r < 4; r++) {
      float s = 0.f;
#pragma unroll
      for (int j = 0; j < 8; j++) s += acc2[i][j][r] * acc2[i][j][r];
      ss[i][r] = s;
    }
#pragma unroll
  for (int m = 1; m < 16; m <<= 1)
#pragma unroll
    for (int i = 0; i < 2; i++)
#pragma unroll
      for (int r = 0; r < 4; r++) ss[i][r] += __shfl_xor(ss[i][r], m, 64);
  if (l16 == 0) {
#pragma unroll
    for (int i = 0; i < 2; i++)
#pragma unroll
      for (int r = 0; r < 4; r++) ssb[wr * 32 + i * 16 + quad * 4 + r][wn] = ss[i][r];
  }
  __syncthreads();   // rownorm combine
  if (tid < 64) {
    float s2 = ssb[tid][0] + ssb[tid][1];
    rn[bm * 64 + tid] = 1.f / fmaxf(sqrtf(s2), EPS);
  }

#pragma unroll
  for (int i = 0; i < 2; i++)
#pragma unroll
    for (int j = 0; j < 8; j++) {
      const int gcol = wn * 128 + j * 16 + l16;
#pragma unroll
      for (int r = 0; r < 4; r++) {
        const size_t grow2 = bm * 64 + wr * 32 + i * 16 + quad * 4 + r;
        G[grow2 * H + gcol] = f2bf(acc2[i][j][r]);
      }
    }
#undef STAGE_A
#undef STAGE_W
}

__device__ __forceinline__ float dot_u4(uint4 a, uint4 b) {
  float s;
  s  = bflo(a.x) * bflo(b.x) + bfhi(a.x) * bfhi(b.x);
  s += bflo(a.y) * bflo(b.y) + bfhi(a.y) * bfhi(b.y);
  s += bflo(a.z) * bflo(b.z) + bfhi(a.z) * bfhi(b.z);
  s += bflo(a.w) * bflo(b.w) + bfhi(a.w) * bfhi(b.w);
  return s;
}

// 8 lanes per edge, 8 edges per wave, 32 edges per block.
__global__ __launch_bounds__(256) void edge_cos_kernel(
    const int* __restrict__ ei, const unsigned short* __restrict__ g,
    const float* __restrict__ rn, float* __restrict__ out, int E) {
  const int lane = threadIdx.x & 63;
  const int wid  = threadIdx.x >> 6;
  const int l8   = lane & 7;
  const int sub  = lane >> 3;
  const int e    = blockIdx.x * 32 + wid * 8 + sub;
  if (e >= E) return;
  const int c = ei[e], r = ei[E + e];
  const uint4* gc = (const uint4*)(g + (size_t)c * H);
  const uint4* gr = (const uint4*)(g + (size_t)r * H);
  uint4 a0 = gc[l8], a1 = gc[l8 + 8], a2 = gc[l8 + 16], a3 = gc[l8 + 24];
  uint4 b0 = gr[l8], b1 = gr[l8 + 8], b2 = gr[l8 + 16], b3 = gr[l8 + 24];
  float d = dot_u4(a0, b0) + dot_u4(a1, b1) + dot_u4(a2, b2) + dot_u4(a3, b3);
  d += __shfl_xor(d, 4, 8);
  d += __shfl_xor(d, 2, 8);
  d += __shfl_xor(d, 1, 8);
  if (l8 == 0) out[e] = d * rn[c] * rn[r];
}

extern "C" void kernel_launch(void* const* d_in, const int* in_sizes, int n_in,
                              void* d_out, int out_size, void* d_ws, size_t ws_size,
                              hipStream_t stream) {
  const float* emb = (const float*)d_in[0];
  const int*   ei  = (const int*)d_in[1];
  const float* W1  = (const float*)d_in[2];
  const float* b1  = (const float*)d_in[3];
  const float* W2  = (const float*)d_in[4];
  const float* b2  = (const float*)d_in[5];
  float* out = (float*)d_out;

  const int NH = in_sizes[0];              // N*H
  const int N  = NH / H;                   // 50000
  const int E  = in_sizes[1] / 2;          // 300000
  const int Mp = ((N + 63) / 64) * 64;     // 50048 (multiple of 64)

  char* ws = (char*)d_ws;
  unsigned short* gB   = (unsigned short*)ws; ws += (size_t)Mp * H * 2;
  unsigned short* w1B  = (unsigned short*)ws; ws += (size_t)H * H * 2;
  unsigned short* w2B  = (unsigned short*)ws; ws += (size_t)H * H * 2;
  float* rn            = (float*)ws;

  conv_w_kernel<<<(2 * H * H / 4 + 255) / 256, 256, 0, stream>>>(W1, W2, w1B, w2B);

  fused_mlp_kernel<<<Mp / 64, 256, 0, stream>>>(emb, w1B, w2B, b1, b2, gB, rn, N);

  edge_cos_kernel<<<(E + 31) / 32, 256, 0, stream>>>(ei, gB, rn, out, E);
}

// Round 12
// 156.503 us; speedup vs baseline: 1.2280x; 1.0067x over previous
//
#include <hip/hip_runtime.h>
#include <stdint.h>

#define H 256
#define EPS 1e-8f

typedef __bf16 bf16x8 __attribute__((ext_vector_type(8)));
typedef float  f32x4  __attribute__((ext_vector_type(4)));

__device__ __forceinline__ unsigned short f2bf(float f) {
  unsigned u = __builtin_bit_cast(unsigned, f);
  u += 0x7FFFu + ((u >> 16) & 1u);            // round-to-nearest-even
  return (unsigned short)(u >> 16);
}
__device__ __forceinline__ float bflo(unsigned u){ return __builtin_bit_cast(float, u << 16); }
__device__ __forceinline__ float bfhi(unsigned u){ return __builtin_bit_cast(float, u & 0xFFFF0000u); }

__device__ __forceinline__ uint4 pack8(float4 a, float4 b) {
  uint4 p;
  p.x = (unsigned)f2bf(a.x) | ((unsigned)f2bf(a.y) << 16);
  p.y = (unsigned)f2bf(a.z) | ((unsigned)f2bf(a.w) << 16);
  p.z = (unsigned)f2bf(b.x) | ((unsigned)f2bf(b.y) << 16);
  p.w = (unsigned)f2bf(b.z) | ((unsigned)f2bf(b.w) << 16);
  return p;
}

// Pre-swizzle both weight matrices into PER-LANE FRAGMENT ORDER (bf16):
//   granule g = wn*4096 + (kt*8+i)*64 + lane   (16 B each, 128 KB per matrix)
//   content  = W[wn*128 + i*16 + (lane&15)][kt*32 + (lane>>4)*8 .. +8]
// With this layout a GEMM fragment load is ONE global_load_dwordx4 whose 64
// lanes are contiguous (1 KB line-sequential, L2-resident) - the fix for
// round-6's 16-line scatter, and it removes the W LDS round-trip entirely.
__global__ __launch_bounds__(256) void conv_w_kernel(
    const float* __restrict__ W1, const float* __restrict__ W2,
    unsigned short* __restrict__ w1S, unsigned short* __restrict__ w2S) {
  int t = blockIdx.x * 256 + threadIdx.x;
  if (t >= 2 * 8192) return;
  const float* src = (t < 8192) ? W1 : W2;
  unsigned short* dst = (t < 8192) ? w1S : w2S;
  int g = t & 8191;
  int wn = g >> 12, rem = g & 4095, f = rem >> 6, lane = rem & 63;
  int kt = f >> 3, i = f & 7, l16 = lane & 15, quad = lane >> 4;
  int row = wn * 128 + i * 16 + l16;
  int k0  = kt * 32 + quad * 8;
  float4 a = *(const float4*)(src + (size_t)row * H + k0);
  float4 b = *(const float4*)(src + (size_t)row * H + k0 + 4);
  *(uint4*)(dst + (size_t)g * 8) = pack8(a, b);
}

// Fused MLP: g = relu(emb@W1^T + b1)@W2^T + b2, plus rn[i] = 1/max(||g_i||,eps).
// Round-12: W FRAGMENTS IN REGISTERS from the pre-swizzled global layout.
// Ledger (rounds 4-11): every schedule AND occupancy variant = 43-47us with
// identical counters -> the invariant per-step critical path is the W LDS
// round-trip + 8 conflicted sW reads + 2 barriers per step. All removed:
//  - wreg[2][8] ring, 2-step lookahead, coalesced dwordx4 loads (L2-resident).
//  - LDS reads/step: 10 -> 2 (just af0/af1 from the 4KB sA).
//  - Barriers: 33 -> 10, all lgkm-only (nothing ever drains vmcnt: W and A
//    global loads stay in flight across every barrier).
//  - GEMM2 is BARRIER-FREE (reads stable sH + W2 regs only).
// A path, sH handoff (m89/m91 layout + XOR swizzle), epilogues byte-identical
// to rounds 4-11 (all passed). LDS = 8K sA dbuf + 32K sH = 40 KB (ssb aliases
// the dead sA).
__global__ __launch_bounds__(256) void fused_mlp_kernel(
    const float* __restrict__ Af,            // emb fp32 [N][H]
    const unsigned short* __restrict__ W1S,  // pre-swizzled, 128 KB
    const unsigned short* __restrict__ W2S,
    const float* __restrict__ b1, const float* __restrict__ b2,
    unsigned short* __restrict__ G,          // gB out [Mp][H] bf16
    float* __restrict__ rn, int N) {
  __shared__ unsigned short sA[2][64 * 32];   // 8 KB emb tile (dbuf)
  __shared__ unsigned short sH[64 * 256];     // 32 KB h (swizzled)
  float (*ssb)[2] = (float(*)[2])sA;          // aliases sA (dead after GEMM1)

  const int tid  = threadIdx.x;
  const int wave = tid >> 6, lane = tid & 63;
  const int quad = lane >> 4, l16 = lane & 15;
  const int wr = wave >> 1, wn = wave & 1;
  const size_t bm = blockIdx.x;

  // A staging geometry (proven): thread -> (row = tid>>2, chunk = tid&3)
  const int arow = tid >> 2, kch = (tid & 3) * 8;
  const int grow = (int)bm * 64 + arow;
  const bool avalid = grow < N;
  const int crow = avalid ? grow : (N - 1);
  const float* gAf = Af + (size_t)crow * H + kch;
  // per-lane W fragment bases: frag (kt,i) at + (kt*8+i)*512 ushorts
  const unsigned short* w1p = W1S + ((size_t)wn * 4096 + lane) * 8;
  const unsigned short* w2p = W2S + ((size_t)wn * 4096 + lane) * 8;

  const float4 z4 = make_float4(0.f, 0.f, 0.f, 0.f);
  float4 rf[2][2];     // A ring (2 slots)
  bf16x8 wreg[2][8];   // W fragment ring (2 k-steps)

#define LOADA(kt, s)                                                            \
  do {                                                                          \
    rf[s][0] = *(const float4*)(gAf + (kt) * 32);                               \
    rf[s][1] = *(const float4*)(gAf + (kt) * 32 + 4);                           \
  } while (0)
#define WRITEA(s)                                                               \
  do {                                                                          \
    float4 t0 = avalid ? rf[s][0] : z4;                                         \
    float4 t1 = avalid ? rf[s][1] : z4;                                         \
    *(uint4*)(&sA[s][tid * 8]) = pack8(t0, t1);                                 \
  } while (0)
#define LOADWF(buf, wp, kt)                                                     \
  do {                                                                          \
    _Pragma("unroll")                                                           \
    for (int i_ = 0; i_ < 8; i_++)                                              \
      wreg[buf][i_] = *(const bf16x8*)((wp) + ((kt) * 8 + i_) * 512);           \
  } while (0)
#define LGKM_BAR()                                                              \
  do {                                                                          \
    asm volatile("s_waitcnt lgkmcnt(0)" ::: "memory");                          \
    __builtin_amdgcn_s_barrier();                                               \
  } while (0)

  // ---------------- GEMM1 (swapped): acc[iC][jR] = h^T subtiles -------------
  f32x4 acc[8][2];
#pragma unroll
  for (int i = 0; i < 8; i++)
#pragma unroll
    for (int j = 0; j < 2; j++) acc[i][j] = (f32x4){0.f, 0.f, 0.f, 0.f};

  // prologue: W1(0),W1(1) + A(0),A(1) in flight; A(0) staged
  LOADWF(0, w1p, 0);
  LOADWF(1, w1p, 1);
  LOADA(0, 0);
  LOADA(1, 1);
  WRITEA(0);
  LGKM_BAR();

#pragma unroll
  for (int kt = 0; kt < 8; ++kt) {
    if (kt < 6) LOADA(kt + 2, kt & 1);       // slot freed by WRITEA at kt-1
    if (kt < 7) WRITEA((kt + 1) & 1);        // ds_write next A tile

    bf16x8 af0, af1;
    af0 = *(const bf16x8*)(&sA[kt & 1][(wr * 32 + 0 * 16 + l16) * 32 + quad * 8]);
    af1 = *(const bf16x8*)(&sA[kt & 1][(wr * 32 + 1 * 16 + l16) * 32 + quad * 8]);

#pragma unroll
    for (int i = 0; i < 8; i++) {
      acc[i][0] = __builtin_amdgcn_mfma_f32_16x16x32_bf16(wreg[kt & 1][i], af0, acc[i][0], 0, 0, 0);
      acc[i][1] = __builtin_amdgcn_mfma_f32_16x16x32_bf16(wreg[kt & 1][i], af1, acc[i][1], 0, 0, 0);
    }

    // refill the just-consumed W buffer (2-step lookahead; WAR on regs is
    // ordered by the compiler's data deps)
    if (kt < 6)       LOADWF(kt & 1, w1p, kt + 2);
    else if (kt == 6) LOADWF(0, w2p, 0);
    else              LOADWF(1, w2p, 1);

    if (kt < 7) LGKM_BAR();                  // lgkm-only: loads stay in flight
  }

  // ------------- h epilogue: +b1, relu, bf16, packed b64 into sH ------------
  // layout (m89/m91-verified, rounds 4-11 passed): lane l16 = h-row, reg = h-col
#pragma unroll
  for (int i = 0; i < 8; i++) {
    const int hcol = wn * 128 + i * 16 + quad * 4;
    const float4 bv = *(const float4*)(b1 + hcol);
#pragma unroll
    for (int j = 0; j < 2; j++) {
      const int row = wr * 32 + j * 16 + l16;
      f32x4 v = acc[i][j];
      unsigned short h0 = f2bf(fmaxf(v[0] + bv.x, 0.f));
      unsigned short h1 = f2bf(fmaxf(v[1] + bv.y, 0.f));
      unsigned short h2 = f2bf(fmaxf(v[2] + bv.z, 0.f));
      unsigned short h3 = f2bf(fmaxf(v[3] + bv.w, 0.f));
      uint2 p;
      p.x = (unsigned)h0 | ((unsigned)h1 << 16);
      p.y = (unsigned)h2 | ((unsigned)h3 << 16);
      unsigned off = (unsigned)(row * 512 + hcol * 2) ^ ((unsigned)(row & 7) << 4);
      *(uint2*)((char*)sH + off) = p;
    }
  }

  LGKM_BAR();   // sH visible; W2(1) load still in flight

  // -------- GEMM2 (normal, BARRIER-FREE): acc2[iR][j] = g subtiles ----------
  f32x4 acc2[2][8];
#pragma unroll
  for (int i = 0; i < 2; i++)
#pragma unroll
    for (int j = 0; j < 8; j++) acc2[i][j] = (f32x4){0.f, 0.f, 0.f, 0.f};

#pragma unroll
  for (int kt = 0; kt < 8; ++kt) {
    bf16x8 hf[2];
#pragma unroll
    for (int i = 0; i < 2; i++) {
      const int hrow = wr * 32 + i * 16 + l16;
      unsigned off = (unsigned)(hrow * 512 + kt * 64 + quad * 16) ^ ((unsigned)(hrow & 7) << 4);
      hf[i] = *(const bf16x8*)((const char*)sH + off);
    }
#pragma unroll
    for (int i = 0; i < 2; i++)
#pragma unroll
      for (int j = 0; j < 8; j++)
        acc2[i][j] = __builtin_amdgcn_mfma_f32_16x16x32_bf16(hf[i], wreg[kt & 1][j], acc2[i][j], 0, 0, 0);
    if (kt < 6) LOADWF(kt & 1, w2p, kt + 2);
  }

  // --------- final epilogue: +b2, rownorm (in-block), bf16 g writes ---------
  float b2v[8];
#pragma unroll
  for (int j = 0; j < 8; j++) b2v[j] = b2[wn * 128 + j * 16 + l16];
#pragma unroll
  for (int i = 0; i < 2; i++)
#pragma unroll
    for (int j = 0; j < 8; j++)
#pragma unroll
      for (int r = 0; r < 4; r++) acc2[i][j][r] += b2v[j];

  float ss[2][4];
#pragma unroll
  for (int i = 0; i < 2; i++)
#pragma unroll
    for (int r = 0; r < 4; r++) {
      float s = 0.f;
#pragma unroll
      for (int j = 0; j < 8; j++) s += acc2[i][j][r] * acc2[i][j][r];
      ss[i][r] = s;
    }
#pragma unroll
  for (int m = 1; m < 16; m <<= 1)
#pragma unroll
    for (int i = 0; i < 2; i++)
#pragma unroll
      for (int r = 0; r < 4; r++) ss[i][r] += __shfl_xor(ss[i][r], m, 64);
  __syncthreads();   // all sA reads long done; safe to alias ssb (drain is fine here)
  if (l16 == 0) {
#pragma unroll
    for (int i = 0; i < 2; i++)
#pragma unroll
      for (int r = 0; r < 4; r++) ssb[wr * 32 + i * 16 + quad * 4 + r][wn] = ss[i][r];
  }
  __syncthreads();   // rownorm combine
  if (tid < 64) {
    float s2 = ssb[tid][0] + ssb[tid][1];
    rn[bm * 64 + tid] = 1.f / fmaxf(sqrtf(s2), EPS);
  }

#pragma unroll
  for (int i = 0; i < 2; i++)
#pragma unroll
    for (int j = 0; j < 8; j++) {
      const int gcol = wn * 128 + j * 16 + l16;
#pragma unroll
      for (int r = 0; r < 4; r++) {
        const size_t grow2 = bm * 64 + wr * 32 + i * 16 + quad * 4 + r;
        G[grow2 * H + gcol] = f2bf(acc2[i][j][r]);
      }
    }
#undef LOADA
#undef WRITEA
#undef LOADWF
#undef LGKM_BAR
}

__device__ __forceinline__ float dot_u4(uint4 a, uint4 b) {
  float s;
  s  = bflo(a.x) * bflo(b.x) + bfhi(a.x) * bfhi(b.x);
  s += bflo(a.y) * bflo(b.y) + bfhi(a.y) * bfhi(b.y);
  s += bflo(a.z) * bflo(b.z) + bfhi(a.z) * bfhi(b.z);
  s += bflo(a.w) * bflo(b.w) + bfhi(a.w) * bfhi(b.w);
  return s;
}

// 8 lanes per edge, 8 edges per wave, 32 edges per block.
__global__ __launch_bounds__(256) void edge_cos_kernel(
    const int* __restrict__ ei, const unsigned short* __restrict__ g,
    const float* __restrict__ rn, float* __restrict__ out, int E) {
  const int lane = threadIdx.x & 63;
  const int wid  = threadIdx.x >> 6;
  const int l8   = lane & 7;
  const int sub  = lane >> 3;
  const int e    = blockIdx.x * 32 + wid * 8 + sub;
  if (e >= E) return;
  const int c = ei[e], r = ei[E + e];
  const uint4* gc = (const uint4*)(g + (size_t)c * H);
  const uint4* gr = (const uint4*)(g + (size_t)r * H);
  uint4 a0 = gc[l8], a1 = gc[l8 + 8], a2 = gc[l8 + 16], a3 = gc[l8 + 24];
  uint4 b0 = gr[l8], b1 = gr[l8 + 8], b2 = gr[l8 + 16], b3 = gr[l8 + 24];
  float d = dot_u4(a0, b0) + dot_u4(a1, b1) + dot_u4(a2, b2) + dot_u4(a3, b3);
  d += __shfl_xor(d, 4, 8);
  d += __shfl_xor(d, 2, 8);
  d += __shfl_xor(d, 1, 8);
  if (l8 == 0) out[e] = d * rn[c] * rn[r];
}

extern "C" void kernel_launch(void* const* d_in, const int* in_sizes, int n_in,
                              void* d_out, int out_size, void* d_ws, size_t ws_size,
                              hipStream_t stream) {
  const float* emb = (const float*)d_in[0];
  const int*   ei  = (const int*)d_in[1];
  const float* W1  = (const float*)d_in[2];
  const float* b1  = (const float*)d_in[3];
  const float* W2  = (const float*)d_in[4];
  const float* b2  = (const float*)d_in[5];
  float* out = (float*)d_out;

  const int NH = in_sizes[0];              // N*H
  const int N  = NH / H;                   // 50000
  const int E  = in_sizes[1] / 2;          // 300000
  const int Mp = ((N + 63) / 64) * 64;     // 50048 (multiple of 64)

  char* ws = (char*)d_ws;
  unsigned short* gB   = (unsigned short*)ws; ws += (size_t)Mp * H * 2;
  unsigned short* w1S  = (unsigned short*)ws; ws += (size_t)H * H * 2;
  unsigned short* w2S  = (unsigned short*)ws; ws += (size_t)H * H * 2;
  float* rn            = (float*)ws;

  conv_w_kernel<<<64, 256, 0, stream>>>(W1, W2, w1S, w2S);

  fused_mlp_kernel<<<Mp / 64, 256, 0, stream>>>(emb, w1S, w2S, b1, b2, gB, rn, N);

  edge_cos_kernel<<<(E + 31) / 32, 256, 0, stream>>>(ei, gB, rn, out, E);
}

// Round 13
// 155.936 us; speedup vs baseline: 1.2325x; 1.0036x over previous
//
#include <hip/hip_runtime.h>
#include <stdint.h>

#define H 256
#define EPS 1e-8f

typedef __bf16 bf16x8 __attribute__((ext_vector_type(8)));
typedef float  f32x4  __attribute__((ext_vector_type(4)));

__device__ __forceinline__ unsigned short f2bf(float f) {
  unsigned u = __builtin_bit_cast(unsigned, f);
  u += 0x7FFFu + ((u >> 16) & 1u);            // round-to-nearest-even
  return (unsigned short)(u >> 16);
}
__device__ __forceinline__ float bflo(unsigned u){ return __builtin_bit_cast(float, u << 16); }
__device__ __forceinline__ float bfhi(unsigned u){ return __builtin_bit_cast(float, u & 0xFFFF0000u); }

__device__ __forceinline__ void g2l16(const void* g, void* l) {
  __builtin_amdgcn_global_load_lds((__attribute__((address_space(1))) void*)g,
                                   (__attribute__((address_space(3))) void*)l, 16, 0, 0);
}

// both 256x256 weight matrices in one launch (grid = 2*H*H/4/256 = 128)
__global__ __launch_bounds__(256) void conv_w_kernel(
    const float* __restrict__ W1, const float* __restrict__ W2,
    unsigned short* __restrict__ w1B, unsigned short* __restrict__ w2B) {
  int i = (blockIdx.x * 256 + threadIdx.x) * 4;
  const int HH = H * H;
  if (i >= 2 * HH) return;
  const float* s = (i < HH) ? W1 : W2;
  unsigned short* d = (i < HH) ? w1B : w2B;
  int j = (i < HH) ? i : i - HH;
  float4 v = *(const float4*)(s + j);
  ushort4 o;
  o.x = f2bf(v.x); o.y = f2bf(v.y); o.z = f2bf(v.z); o.w = f2bf(v.w);
  *(ushort4*)(d + j) = o;
}

// Fused MLP: g = relu(emb@W1^T + b1)@W2^T + b2; writes G = g * (1/max(||g||,eps))
// (normalization FOLDED into the G write - edge_cos no longer needs rn).
// Round-13 = round-5 fused structure VERBATIM (best measured: 43.3us), which
// the rounds 6-12 ledger never beat (8 variants, 43-57us - the 2-phase
// plateau of the regime-gate table; T2/T4/T5 all null as predicted there).
// Only change: final epilogue computes per-lane rinv from ssb and scales g
// before the bf16 store; rn global buffer deleted.
__global__ __launch_bounds__(256) void fused_mlp_kernel(
    const float* __restrict__ Af,           // emb fp32 [N][H]
    const unsigned short* __restrict__ W1,  // [H][H] bf16, row = out-col
    const unsigned short* __restrict__ W2,
    const float* __restrict__ b1, const float* __restrict__ b2,
    unsigned short* __restrict__ G,         // gB out [Mp][H] bf16, NORMALIZED
    int N) {
  __shared__ unsigned short sA[2][64 * 32];   // 8 KB  emb tile (dbuf)
  __shared__ unsigned short sW[2][256 * 32];  // 32 KB weight tile (dbuf, W1 then W2)
  __shared__ unsigned short sH[64 * 256];     // 32 KB h (swizzled)
  __shared__ float ssb[64][2];                // rownorm partials per col-half

  const int tid  = threadIdx.x;
  const int wave = tid >> 6, lane = tid & 63;
  const int quad = lane >> 4, l16 = lane & 15;
  const int wr = wave >> 1, wn = wave & 1;
  const size_t bm = blockIdx.x;

  // staging geometry: thread -> (row, 8-elem k-chunk); sA/sW are row-major [r][32]
  const int arow = tid >> 2, kch = (tid & 3) * 8;
  const int grow = (int)bm * 64 + arow;
  const bool avalid = grow < N;
  const float* gAf = Af + (size_t)(avalid ? grow : 0) * H + kch;
  const unsigned short* gW1 = W1 + (size_t)arow * H + kch;
  const unsigned short* gW2 = W2 + (size_t)arow * H + kch;

  float4 ra[3][2];
#define LOAD_A(kt, slot)                                                        \
  do {                                                                          \
    if (avalid) {                                                               \
      ra[slot][0] = *(const float4*)(gAf + (kt) * 32);                          \
      ra[slot][1] = *(const float4*)(gAf + (kt) * 32 + 4);                      \
    } else {                                                                    \
      ra[slot][0] = make_float4(0.f, 0.f, 0.f, 0.f);                            \
      ra[slot][1] = make_float4(0.f, 0.f, 0.f, 0.f);                            \
    }                                                                           \
  } while (0)
#define WRITE_A(buf, slot)                                                      \
  do {                                                                          \
    uint4 p;                                                                    \
    p.x = (unsigned)f2bf(ra[slot][0].x) | ((unsigned)f2bf(ra[slot][0].y) << 16);\
    p.y = (unsigned)f2bf(ra[slot][0].z) | ((unsigned)f2bf(ra[slot][0].w) << 16);\
    p.z = (unsigned)f2bf(ra[slot][1].x) | ((unsigned)f2bf(ra[slot][1].y) << 16);\
    p.w = (unsigned)f2bf(ra[slot][1].z) | ((unsigned)f2bf(ra[slot][1].w) << 16);\
    *(uint4*)(&sA[buf][tid * 8]) = p;                                           \
  } while (0)
#define STAGE_W(gW, kt, buf)                                                    \
  do {                                                                          \
    _Pragma("unroll")                                                           \
    for (int c = 0; c < 4; c++)                                                 \
      g2l16((gW) + (size_t)(c * 64) * H + (kt) * 32, &sW[buf][c * 2048 + tid * 8]); \
  } while (0)

  // ---------------- GEMM1 (swapped): acc[iC][jR] = h^T subtiles -------------
  f32x4 acc[8][2];
#pragma unroll
  for (int i = 0; i < 8; i++)
#pragma unroll
    for (int j = 0; j < 2; j++) acc[i][j] = (f32x4){0.f, 0.f, 0.f, 0.f};

  // prologue: A for kt=0..2 in flight, A0 + W1_0 staged
  LOAD_A(0, 0); LOAD_A(1, 1); LOAD_A(2, 2);
  WRITE_A(0, 0);
  STAGE_W(gW1, 0, 0);
  __syncthreads();

#pragma unroll
  for (int kt = 0; kt < 8; ++kt) {
    if (kt < 5) LOAD_A(kt + 3, (kt + 3) % 3);            // 3-ahead HBM prefetch
    if (kt < 7) STAGE_W(gW1, kt + 1, (kt + 1) & 1);      // 1-ahead L2 prefetch
    if (kt == 7) STAGE_W(gW2, 0, 0);                     // W2_0 into freed half

    bf16x8 wf[8], af[2];
#pragma unroll
    for (int i = 0; i < 8; i++)
      wf[i] = *(const bf16x8*)(&sW[kt & 1][(wn * 128 + i * 16 + l16) * 32 + quad * 8]);
#pragma unroll
    for (int j = 0; j < 2; j++)
      af[j] = *(const bf16x8*)(&sA[kt & 1][(wr * 32 + j * 16 + l16) * 32 + quad * 8]);

    if (kt < 7) WRITE_A((kt + 1) & 1, (kt + 1) % 3);     // cvt + ds_write next A

#pragma unroll
    for (int i = 0; i < 8; i++)
#pragma unroll
      for (int j = 0; j < 2; j++)
        acc[i][j] = __builtin_amdgcn_mfma_f32_16x16x32_bf16(wf[i], af[j], acc[i][j], 0, 0, 0);
    __syncthreads();   // single barrier per k-step: stages drained, reads done
  }

  // ------------- h epilogue: +b1, relu, bf16, packed b64 into sH ------------
  // layout (m89/m91-verified, rounds 4-12 passed): lane l16 = h-row, reg = h-col
#pragma unroll
  for (int i = 0; i < 8; i++) {
    const int hcol = wn * 128 + i * 16 + quad * 4;
    const float4 bv = *(const float4*)(b1 + hcol);
#pragma unroll
    for (int j = 0; j < 2; j++) {
      const int row = wr * 32 + j * 16 + l16;
      f32x4 v = acc[i][j];
      unsigned short h0 = f2bf(fmaxf(v[0] + bv.x, 0.f));
      unsigned short h1 = f2bf(fmaxf(v[1] + bv.y, 0.f));
      unsigned short h2 = f2bf(fmaxf(v[2] + bv.z, 0.f));
      unsigned short h3 = f2bf(fmaxf(v[3] + bv.w, 0.f));
      uint2 p;
      p.x = (unsigned)h0 | ((unsigned)h1 << 16);
      p.y = (unsigned)h2 | ((unsigned)h3 << 16);
      unsigned off = (unsigned)(row * 512 + hcol * 2) ^ ((unsigned)(row & 7) << 4);
      *(uint2*)((char*)sH + off) = p;
    }
  }

  __syncthreads();   // sH visible; W2_0 drained

  // ---------------- GEMM2 (normal): acc2[iR][j] = g subtiles ----------------
  f32x4 acc2[2][8];
#pragma unroll
  for (int i = 0; i < 2; i++)
#pragma unroll
    for (int j = 0; j < 8; j++) acc2[i][j] = (f32x4){0.f, 0.f, 0.f, 0.f};

#pragma unroll
  for (int kt = 0; kt < 8; ++kt) {
    if (kt < 7) STAGE_W(gW2, kt + 1, (kt + 1) & 1);      // issue-early prefetch

    bf16x8 hf[2], wf2[8];
#pragma unroll
    for (int i = 0; i < 2; i++) {
      const int hrow = wr * 32 + i * 16 + l16;
      unsigned off = (unsigned)(hrow * 512 + kt * 64 + quad * 16) ^ ((unsigned)(hrow & 7) << 4);
      hf[i] = *(const bf16x8*)((const char*)sH + off);
    }
#pragma unroll
    for (int j = 0; j < 8; j++)
      wf2[j] = *(const bf16x8*)(&sW[kt & 1][(wn * 128 + j * 16 + l16) * 32 + quad * 8]);
#pragma unroll
    for (int i = 0; i < 2; i++)
#pragma unroll
      for (int j = 0; j < 8; j++)
        acc2[i][j] = __builtin_amdgcn_mfma_f32_16x16x32_bf16(hf[i], wf2[j], acc2[i][j], 0, 0, 0);
    __syncthreads();
  }

  // ---- final epilogue: +b2, rownorm reduce, NORMALIZED bf16 g writes -------
  float b2v[8];
#pragma unroll
  for (int j = 0; j < 8; j++) b2v[j] = b2[wn * 128 + j * 16 + l16];
#pragma unroll
  for (int i = 0; i < 2; i++)
#pragma unroll
    for (int j = 0; j < 8; j++)
#pragma unroll
      for (int r = 0; r < 4; r++) acc2[i][j][r] += b2v[j];

  float ss[2][4];
#pragma unroll
  for (int i = 0; i < 2; i++)
#pragma unroll
    for (int r = 0; r < 4; r++) {
      float s = 0.f;
#pragma unroll
      for (int j = 0; j < 8; j++) s += acc2[i][j][r] * acc2[i][j][r];
      ss[i][r] = s;
    }
#pragma unroll
  for (int m = 1; m < 16; m <<= 1)
#pragma unroll
    for (int i = 0; i < 2; i++)
#pragma unroll
      for (int r = 0; r < 4; r++) ss[i][r] += __shfl_xor(ss[i][r], m, 64);
  if (l16 == 0) {
#pragma unroll
    for (int i = 0; i < 2; i++)
#pragma unroll
      for (int r = 0; r < 4; r++) ssb[wr * 32 + i * 16 + quad * 4 + r][wn] = ss[i][r];
  }
  __syncthreads();   // ssb complete (both col-halves)

  // per-lane reciprocal norms for the 8 rows this lane writes (LDS broadcast
  // reads: lanes sharing a row hit the same address - conflict-free)
  float rinv[2][4];
#pragma unroll
  for (int i = 0; i < 2; i++)
#pragma unroll
    for (int r = 0; r < 4; r++) {
      const int lrow = wr * 32 + i * 16 + quad * 4 + r;
      float s2 = ssb[lrow][0] + ssb[lrow][1];
      rinv[i][r] = 1.f / fmaxf(sqrtf(s2), EPS);
    }

#pragma unroll
  for (int i = 0; i < 2; i++)
#pragma unroll
    for (int j = 0; j < 8; j++) {
      const int gcol = wn * 128 + j * 16 + l16;
#pragma unroll
      for (int r = 0; r < 4; r++) {
        const size_t grow2 = bm * 64 + wr * 32 + i * 16 + quad * 4 + r;
        G[grow2 * H + gcol] = f2bf(acc2[i][j][r] * rinv[i][r]);
      }
    }
#undef LOAD_A
#undef WRITE_A
#undef STAGE_W
}

__device__ __forceinline__ float dot_u4(uint4 a, uint4 b) {
  float s;
  s  = bflo(a.x) * bflo(b.x) + bfhi(a.x) * bfhi(b.x);
  s += bflo(a.y) * bflo(b.y) + bfhi(a.y) * bfhi(b.y);
  s += bflo(a.z) * bflo(b.z) + bfhi(a.z) * bfhi(b.z);
  s += bflo(a.w) * bflo(b.w) + bfhi(a.w) * bfhi(b.w);
  return s;
}

// 8 lanes per edge, 8 edges per wave, 32 edges per block.
// g rows are PRE-NORMALIZED -> out = plain dot (rn gathers eliminated).
__global__ __launch_bounds__(256) void edge_cos_kernel(
    const int* __restrict__ ei, const unsigned short* __restrict__ g,
    float* __restrict__ out, int E) {
  const int lane = threadIdx.x & 63;
  const int wid  = threadIdx.x >> 6;
  const int l8   = lane & 7;
  const int sub  = lane >> 3;
  const int e    = blockIdx.x * 32 + wid * 8 + sub;
  if (e >= E) return;
  const int c = ei[e], r = ei[E + e];
  const uint4* gc = (const uint4*)(g + (size_t)c * H);
  const uint4* gr = (const uint4*)(g + (size_t)r * H);
  uint4 a0 = gc[l8], a1 = gc[l8 + 8], a2 = gc[l8 + 16], a3 = gc[l8 + 24];
  uint4 b0 = gr[l8], b1 = gr[l8 + 8], b2 = gr[l8 + 16], b3 = gr[l8 + 24];
  float d = dot_u4(a0, b0) + dot_u4(a1, b1) + dot_u4(a2, b2) + dot_u4(a3, b3);
  d += __shfl_xor(d, 4, 8);
  d += __shfl_xor(d, 2, 8);
  d += __shfl_xor(d, 1, 8);
  if (l8 == 0) out[e] = d;
}

extern "C" void kernel_launch(void* const* d_in, const int* in_sizes, int n_in,
                              void* d_out, int out_size, void* d_ws, size_t ws_size,
                              hipStream_t stream) {
  const float* emb = (const float*)d_in[0];
  const int*   ei  = (const int*)d_in[1];
  const float* W1  = (const float*)d_in[2];
  const float* b1  = (const float*)d_in[3];
  const float* W2  = (const float*)d_in[4];
  const float* b2  = (const float*)d_in[5];
  float* out = (float*)d_out;

  const int NH = in_sizes[0];              // N*H
  const int N  = NH / H;                   // 50000
  const int E  = in_sizes[1] / 2;          // 300000
  const int Mp = ((N + 63) / 64) * 64;     // 50048 (multiple of 64)

  char* ws = (char*)d_ws;
  unsigned short* gB   = (unsigned short*)ws; ws += (size_t)Mp * H * 2;
  unsigned short* w1B  = (unsigned short*)ws; ws += (size_t)H * H * 2;
  unsigned short* w2B  = (unsigned short*)ws; ws += (size_t)H * H * 2;

  conv_w_kernel<<<(2 * H * H / 4 + 255) / 256, 256, 0, stream>>>(W1, W2, w1B, w2B);

  fused_mlp_kernel<<<Mp / 64, 256, 0, stream>>>(emb, w1B, w2B, b1, b2, gB, N);

  edge_cos_kernel<<<(E + 31) / 32, 256, 0, stream>>>(ei, gB, out, E);
}